// Round 9
// baseline (1102.760 us; speedup 1.0000x reference)
//
#include <hip/hip_runtime.h>

#define B_   128
#define T_   16

typedef __bf16 bf16;
typedef __bf16 bf16x4 __attribute__((ext_vector_type(4)));
typedef __bf16 bf16x8 __attribute__((ext_vector_type(8)));
typedef float f32x4 __attribute__((ext_vector_type(4)));

#define GLL(SRC, DST) __builtin_amdgcn_global_load_lds( \
    (const __attribute__((address_space(1))) void*)(SRC), \
    (__attribute__((address_space(3))) void*)(DST), 16, 0, 0)

#define MFMA __builtin_amdgcn_mfma_f32_16x16x32_bf16

__device__ __forceinline__ float sigf(float x) { return 1.f / (1.f + expf(-x)); }

// ---------------------------------------------------------------------------
// Split-K GEMM -> bf16 partial slices. Tile 128x128, BK=64, dbuf LDS,
// grid (32 nt, Z zz). slice = (zz*32+nt), layout 128x128 row-major bf16.
// ---------------------------------------------------------------------------
__global__ __launch_bounds__(256) void gemm_bp(
    const bf16* __restrict__ A, int lda,
    const bf16* __restrict__ W, int ldw, int Kc,
    bf16* __restrict__ part)
{
    __shared__ bf16 As[2][8192];
    __shared__ bf16 Bs[2][8192];

    const int nt = blockIdx.x, zz = blockIdx.y;
    const int tid = threadIdx.x, lane = tid & 63, wave = tid >> 6;
    const bf16* Ab = A + (size_t)zz * Kc;
    const bf16* Wb = W + (size_t)nt * 128 * ldw + (size_t)zz * Kc;

    const int srow = lane >> 3;
    const int scol = ((lane & 7) ^ srow) << 3;

    f32x4 acc[4][4];
#pragma unroll
    for (int m = 0; m < 4; ++m)
#pragma unroll
        for (int n = 0; n < 4; ++n) acc[m][n] = (f32x4){0.f, 0.f, 0.f, 0.f};

    const int wm = wave & 1, wn = wave >> 1;
    const int ln = lane & 15;
    const int rA = wm * 64 + ln;
    const int rB = wn * 64 + ln;
    const int swz = (lane & 7) << 4;
    const int kq  = (lane >> 4) << 4;

    auto stage = [&](int b, int koff) {
#pragma unroll
        for (int i = 0; i < 4; ++i) {
            int rb = i * 32 + wave * 8;
            GLL(Ab + (size_t)(rb + srow) * lda + koff + scol, &As[b][rb * 64]);
            GLL(Wb + (size_t)(rb + srow) * ldw + koff + scol, &Bs[b][rb * 64]);
        }
    };

    const int nk = Kc >> 6;
    stage(0, 0);
    int bq = 0;
    for (int it = 0; it < nk; ++it) {
        __syncthreads();
        if (it + 1 < nk) stage(bq ^ 1, (it + 1) << 6);
        const bf16* as = As[bq];
        const bf16* bs = Bs[bq];
#pragma unroll
        for (int k2 = 0; k2 < 2; ++k2) {
            const int co = (((k2 << 6) | kq) ^ swz) >> 1;
            bf16x8 a[4], b[4];
#pragma unroll
            for (int f = 0; f < 4; ++f) a[f] = *(const bf16x8*)&as[(rA + f * 16) * 64 + co];
#pragma unroll
            for (int f = 0; f < 4; ++f) b[f] = *(const bf16x8*)&bs[(rB + f * 16) * 64 + co];
#pragma unroll
            for (int m = 0; m < 4; ++m)
#pragma unroll
                for (int n = 0; n < 4; ++n)
                    acc[m][n] = MFMA(a[m], b[n], acc[m][n], 0, 0, 0);
        }
        bq ^= 1;
    }

    bf16* myp = part + ((size_t)(zz * gridDim.x + nt)) * 16384;
    const int q = lane >> 4;
#pragma unroll
    for (int m = 0; m < 4; ++m) {
        int row = wm * 64 + m * 16 + q * 4;
#pragma unroll
        for (int n = 0; n < 4; ++n) {
            int col = wn * 64 + n * 16 + ln;
#pragma unroll
            for (int r = 0; r < 4; ++r)
                myp[(size_t)(row + r) * 128 + col] = (bf16)acc[m][n][r];
        }
    }
}

// ---------------------------------------------------------------------------
// kB: sum 16 bf16 slices + base + hdP(4) + heP(4) -> enc LSTM -> henc.
// grid 512 x 256, one gate-quad per thread.
// ---------------------------------------------------------------------------
__global__ __launch_bounds__(256) void kB_k(
    const bf16* __restrict__ part, const float* __restrict__ base,
    const bf16* __restrict__ hdP, const bf16* __restrict__ heP,
    float* __restrict__ c_enc, bf16* __restrict__ henc)
{
    const int i = blockIdx.x * 256 + threadIdx.x;
    const int row = i >> 10, j = i & 1023;
    const size_t off = (size_t)(j >> 5) * 16384 + (size_t)row * 128 + ((j & 31) << 2);

    float s0 = 0.f, s1 = 0.f, s2 = 0.f, s3 = 0.f;
    const bf16* p = part + off;
#pragma unroll
    for (int z = 0; z < 16; ++z) {
        bf16x4 v = *(const bf16x4*)(p + (size_t)z * 524288);
        s0 += (float)v[0]; s1 += (float)v[1]; s2 += (float)v[2]; s3 += (float)v[3];
    }
    const bf16* hp = hdP + off;
    const bf16* ep = heP + off;
#pragma unroll
    for (int z = 0; z < 4; ++z) {
        bf16x4 a = *(const bf16x4*)(hp + (size_t)z * 524288);
        bf16x4 b = *(const bf16x4*)(ep + (size_t)z * 524288);
        s0 += (float)a[0] + (float)b[0]; s1 += (float)a[1] + (float)b[1];
        s2 += (float)a[2] + (float)b[2]; s3 += (float)a[3] + (float)b[3];
    }
    float4 bb = *(const float4*)(base + (size_t)row * 4096 + (j << 2));
    float gi = s0 + bb.x, gf = s1 + bb.y, gg = s2 + bb.z, go = s3 + bb.w;
    float cn = sigf(gf) * c_enc[i] + sigf(gi) * tanhf(gg);
    c_enc[i] = cn;
    henc[i] = (bf16)(sigf(go) * tanhf(cn));
}

// ---------------------------------------------------------------------------
// fin0: sum 16 bf16 slices + both enc biases -> base fp32. grid 512 x 256.
// ---------------------------------------------------------------------------
__global__ __launch_bounds__(256) void fin0_k(
    const bf16* __restrict__ part, float* __restrict__ base,
    const float* __restrict__ b1, const float* __restrict__ b2)
{
    const int i = blockIdx.x * 256 + threadIdx.x;
    const int row = i >> 10, j = i & 1023;
    const size_t off = (size_t)(j >> 5) * 16384 + (size_t)row * 128 + ((j & 31) << 2);
    float s0 = 0.f, s1 = 0.f, s2 = 0.f, s3 = 0.f;
    const bf16* p = part + off;
#pragma unroll
    for (int z = 0; z < 16; ++z) {
        bf16x4 v = *(const bf16x4*)(p + (size_t)z * 524288);
        s0 += (float)v[0]; s1 += (float)v[1]; s2 += (float)v[2]; s3 += (float)v[3];
    }
    int nb = row * 4096 + (j << 2);
    base[nb + 0] = s0 + b1[j]        + b2[j];
    base[nb + 1] = s1 + b1[1024 + j] + b2[1024 + j];
    base[nb + 2] = s2 + b1[2048 + j] + b2[2048 + j];
    base[nb + 3] = s3 + b1[3072 + j] + b2[3072 + j];
}

// ---------------------------------------------------------------------------
// kE: grid 416 (in loop) / 384 (preloop).
//  bid<384: roles 1..3, split-K z=4 (Kc=256, nk=4) -> bf16 slices
//    role1: hdec@Wd_e -> hdP; role2: henc@We_e -> heP; role3: hdec@Wdh -> gdhhP
//  bid>=384: role0 wr: hdec@Wwr full K=1024 (nk=16), fp32 epilogue:
//    c_t += +b_wr -> negs = -sig(c_t), opt out.
// ---------------------------------------------------------------------------
struct SmR { bf16 A[2][8192]; bf16 B[2][8192]; };  // 64 KB

__global__ __launch_bounds__(256) void kE_k(
    const bf16* __restrict__ hdec, const bf16* __restrict__ henc,
    const bf16* __restrict__ Wwr,  const bf16* __restrict__ Wd_e,
    const bf16* __restrict__ We_e, const bf16* __restrict__ Wdh,
    float* __restrict__ c_t, bf16* __restrict__ negs,
    bf16* __restrict__ hdP, bf16* __restrict__ heP,
    bf16* __restrict__ gdhhP, const float* __restrict__ b_wr,
    float* __restrict__ outp)
{
    __shared__ SmR sm;
    const int bid = blockIdx.x;
    const int tid = threadIdx.x, lane = tid & 63, wave = tid >> 6;
    const int srow = lane >> 3;
    const int scol = ((lane & 7) ^ srow) << 3;
    const int wm = wave & 1, wn = wave >> 1;
    const int ln = lane & 15;
    const int rA = wm * 64 + ln;
    const int rB = wn * 64 + ln;
    const int swz = (lane & 7) << 4;
    const int kq  = (lane >> 4) << 4;
    const int q   = lane >> 4;

    int role, nt, zc;
    if (bid < 384) { role = 1 + (bid >> 7); int sub = bid & 127; nt = sub >> 2; zc = sub & 3; }
    else           { role = 0; nt = bid - 384; zc = 0; }

    const bf16* A = (role == 2) ? henc : hdec;
    const bf16* W = (role == 0) ? Wwr : (role == 1) ? Wd_e : (role == 2) ? We_e : Wdh;
    const bf16* Ab = A + zc * 256;
    const bf16* Wb = W + (size_t)nt * 128 * 1024 + zc * 256;
    const int nk = (role == 0) ? 16 : 4;

    f32x4 acc[4][4];
#pragma unroll
    for (int m = 0; m < 4; ++m)
#pragma unroll
        for (int n = 0; n < 4; ++n) acc[m][n] = (f32x4){0.f, 0.f, 0.f, 0.f};

    auto stage = [&](int b, int koff) {
#pragma unroll
        for (int i = 0; i < 4; ++i) {
            int rb = i * 32 + wave * 8;
            GLL(Ab + (size_t)(rb + srow) * 1024 + koff + scol, &sm.A[b][rb * 64]);
            GLL(Wb + (size_t)(rb + srow) * 1024 + koff + scol, &sm.B[b][rb * 64]);
        }
    };

    stage(0, 0);
    int bq = 0;
    for (int it = 0; it < nk; ++it) {
        __syncthreads();
        if (it + 1 < nk) stage(bq ^ 1, (it + 1) << 6);
        const bf16* as = sm.A[bq];
        const bf16* bs = sm.B[bq];
#pragma unroll
        for (int k2 = 0; k2 < 2; ++k2) {
            const int co = (((k2 << 6) | kq) ^ swz) >> 1;
            bf16x8 a[4], b[4];
#pragma unroll
            for (int f = 0; f < 4; ++f) a[f] = *(const bf16x8*)&as[(rA + f * 16) * 64 + co];
#pragma unroll
            for (int f = 0; f < 4; ++f) b[f] = *(const bf16x8*)&bs[(rB + f * 16) * 64 + co];
#pragma unroll
            for (int m = 0; m < 4; ++m)
#pragma unroll
                for (int n = 0; n < 4; ++n)
                    acc[m][n] = MFMA(a[m], b[n], acc[m][n], 0, 0, 0);
        }
        bq ^= 1;
    }

    if (role != 0) {
        bf16* P = (role == 1) ? hdP : (role == 2) ? heP : gdhhP;
        bf16* myp = P + ((size_t)(zc * 32 + nt)) * 16384;
#pragma unroll
        for (int m = 0; m < 4; ++m) {
            int row = wm * 64 + m * 16 + q * 4;
#pragma unroll
            for (int n = 0; n < 4; ++n) {
                int col = wn * 64 + n * 16 + ln;
#pragma unroll
                for (int r = 0; r < 4; ++r)
                    myp[(size_t)(row + r) * 128 + col] = (bf16)acc[m][n][r];
            }
        }
        return;
    }

    // role 0: acc -> LDS fp32 128x128, fused c_t / negs / out epilogue
    __syncthreads();
    float* Cl = (float*)&sm;
#pragma unroll
    for (int m = 0; m < 4; ++m) {
        int row = wm * 64 + m * 16 + q * 4;
#pragma unroll
        for (int n = 0; n < 4; ++n) {
            int col = wn * 64 + n * 16 + ln;
#pragma unroll
            for (int r = 0; r < 4; ++r)
                Cl[(row + r) * 128 + col] = acc[m][n][r];
        }
    }
    __syncthreads();
#pragma unroll
    for (int it = 0; it < 16; ++it) {
        int li = it * 256 + tid;
        int row = li >> 5, cq = li & 31;
        int n0 = nt * 128 + cq * 4;
        int ci = row * 4096 + n0;
        float4 cv = *(const float4*)(c_t + ci);
        float4 ac = *(const float4*)(Cl + row * 128 + cq * 4);
        float4 bw = *(const float4*)(b_wr + n0);
        float v0 = cv.x + ac.x + bw.x, v1 = cv.y + ac.y + bw.y;
        float v2 = cv.z + ac.z + bw.z, v3 = cv.w + ac.w + bw.w;
        *(float4*)(c_t + ci) = make_float4(v0, v1, v2, v3);
        negs[(size_t)row * 4096 + n0 + 0] = (bf16)(-sigf(v0));
        negs[(size_t)row * 4096 + n0 + 1] = (bf16)(-sigf(v1));
        negs[(size_t)row * 4096 + n0 + 2] = (bf16)(-sigf(v2));
        negs[(size_t)row * 4096 + n0 + 3] = (bf16)(-sigf(v3));
        if (outp)
            *(float4*)(outp + ci) = make_float4(sigf(v0), sigf(v1), sigf(v2), sigf(v3));
    }
}

// ---------------------------------------------------------------------------
// kC: mu/sigma GEMM (tile 128x32, K=1024 as 4x256) + reparam -> zbf. grid 16.
// ---------------------------------------------------------------------------
struct SmemG32 {
    bf16 As[4][128][64];   // 64 KB
    bf16 Ws[4][32][64];    // 16 KB
};

__global__ __launch_bounds__(256) void kC_k(
    const bf16* __restrict__ henc, const bf16* __restrict__ Wms,
    const float* __restrict__ b_mu, const float* __restrict__ b_sig,
    const float* __restrict__ eps_t, bf16* __restrict__ zbf)
{
    __shared__ SmemG32 sm;
    const int nt = blockIdx.x;
    const int tid = threadIdx.x, lane = tid & 63, wave = tid >> 6;
    const int srow = lane >> 3, scol = ((lane & 7) ^ srow) << 3;
    const int ln = lane & 15, kq = (lane >> 4) << 4;
    const int swz = (lane & 7) << 4;
    const int rA = wave * 32 + ln;
    const bf16* Wb = Wms + (size_t)nt * 32 * 1024;

    f32x4 acc[2][2];
#pragma unroll
    for (int m = 0; m < 2; ++m)
#pragma unroll
        for (int n = 0; n < 2; ++n) acc[m][n] = (f32x4){0.f, 0.f, 0.f, 0.f};

    for (int it = 0; it < 4; ++it) {
        if (it) __syncthreads();
        const int koff = it * 256;
#pragma unroll
        for (int kc = 0; kc < 4; ++kc) {
            const int kg = koff + kc * 64 + scol;
#pragma unroll
            for (int i = 0; i < 4; ++i) {
                int rb = i * 32 + wave * 8;
                GLL(henc + (size_t)(rb + srow) * 1024 + kg, &sm.As[kc][rb][0]);
            }
            GLL(Wb + (size_t)(wave * 8 + srow) * 1024 + kg, &sm.Ws[kc][wave * 8][0]);
        }
        __syncthreads();
#pragma unroll
        for (int kc = 0; kc < 4; ++kc)
#pragma unroll
            for (int k2 = 0; k2 < 2; ++k2) {
                const int co = (((k2 << 6) | kq) ^ swz) >> 1;
                bf16x8 a0 = *(const bf16x8*)&sm.As[kc][rA][co];
                bf16x8 a1 = *(const bf16x8*)&sm.As[kc][rA + 16][co];
                bf16x8 b0 = *(const bf16x8*)&sm.Ws[kc][ln][co];
                bf16x8 b1 = *(const bf16x8*)&sm.Ws[kc][ln + 16][co];
                acc[0][0] = MFMA(a0, b0, acc[0][0], 0, 0, 0);
                acc[0][1] = MFMA(a0, b1, acc[0][1], 0, 0, 0);
                acc[1][0] = MFMA(a1, b0, acc[1][0], 0, 0, 0);
                acc[1][1] = MFMA(a1, b1, acc[1][1], 0, 0, 0);
            }
    }
    __syncthreads();

    float* Cl = (float*)&sm;
    const int q = lane >> 4;
#pragma unroll
    for (int f = 0; f < 2; ++f)
#pragma unroll
        for (int n = 0; n < 2; ++n)
#pragma unroll
            for (int r = 0; r < 4; ++r)
                Cl[(wave * 32 + f * 16 + q * 4 + r) * 33 + n * 16 + ln] = acc[f][n][r];
    __syncthreads();

#pragma unroll
    for (int it = 0; it < 8; ++it) {
        int li = it * 256 + tid;
        int row = li >> 4, zl = li & 15;
        int zi = nt * 16 + zl;
        float mu = Cl[row * 33 + zl * 2]     + b_mu[zi];
        float ls = Cl[row * 33 + zl * 2 + 1] + b_sig[zi];
        float z = eps_t[row * 256 + zi] * expf(ls) + mu;
        zbf[(size_t)row * 256 + zi] = (bf16)z;
    }
}

// ---------------------------------------------------------------------------
// kD: dec z-part (K=256, one-shot) + gdhh slices + biases + LSTM -> hdec.
// grid 64.
// ---------------------------------------------------------------------------
struct SmemD {
    bf16 As[4][128][64];   // 64 KB
    bf16 Ws[4][64][64];    // 32 KB
};

__global__ __launch_bounds__(256) void kD_k(
    const bf16* __restrict__ zbf, const bf16* __restrict__ Wdz,
    const bf16* __restrict__ gdhhP,
    const float* __restrict__ b_ihd, const float* __restrict__ b_hhd,
    float* __restrict__ c_dec, bf16* __restrict__ hdec)
{
    __shared__ SmemD sm;
    const int nt = blockIdx.x;
    const int tid = threadIdx.x, lane = tid & 63, wave = tid >> 6;
    const int srow = lane >> 3, scol = ((lane & 7) ^ srow) << 3;
    const int ln = lane & 15, q = lane >> 4;
    const int kq = q << 4, swz = (lane & 7) << 4;
    const int wr = wave & 1, wc = wave >> 1;
    const bf16* Wb = Wdz + (size_t)nt * 64 * 256;

    f32x4 acc[4][2];
#pragma unroll
    for (int f = 0; f < 4; ++f)
#pragma unroll
        for (int n = 0; n < 2; ++n) acc[f][n] = (f32x4){0.f, 0.f, 0.f, 0.f};

#pragma unroll
    for (int kc = 0; kc < 4; ++kc) {
        const int kg = kc * 64 + scol;
#pragma unroll
        for (int i = 0; i < 4; ++i) {
            int rb = i * 32 + wave * 8;
            GLL(zbf + (size_t)(rb + srow) * 256 + kg, &sm.As[kc][rb][0]);
        }
#pragma unroll
        for (int i = 0; i < 2; ++i) {
            int rbw = i * 32 + wave * 8;
            GLL(Wb + (size_t)(rbw + srow) * 256 + kg, &sm.Ws[kc][rbw][0]);
        }
    }
    __syncthreads();
#pragma unroll
    for (int kc = 0; kc < 4; ++kc)
#pragma unroll
        for (int k2 = 0; k2 < 2; ++k2) {
            const int co = (((k2 << 6) | kq) ^ swz) >> 1;
            bf16x8 b0 = *(const bf16x8*)&sm.Ws[kc][wc * 32 + ln][co];
            bf16x8 b1 = *(const bf16x8*)&sm.Ws[kc][wc * 32 + ln + 16][co];
#pragma unroll
            for (int f = 0; f < 4; ++f) {
                bf16x8 a = *(const bf16x8*)&sm.As[kc][wr * 64 + f * 16 + ln][co];
                acc[f][0] = MFMA(a, b0, acc[f][0], 0, 0, 0);
                acc[f][1] = MFMA(a, b1, acc[f][1], 0, 0, 0);
            }
        }
    __syncthreads();

    float* Cl = (float*)&sm;
#pragma unroll
    for (int f = 0; f < 4; ++f)
#pragma unroll
        for (int n = 0; n < 2; ++n)
#pragma unroll
            for (int r = 0; r < 4; ++r)
                Cl[(wr * 64 + f * 16 + q * 4 + r) * 66 + wc * 32 + n * 16 + ln] = acc[f][n][r];
    __syncthreads();

#pragma unroll
    for (int it = 0; it < 8; ++it) {
        int li = it * 256 + tid;
        int row = li >> 4, jl = li & 15;
        int J = nt * 16 + jl;
        const float* cr = &Cl[row * 66 + jl * 4];
        int gcol = nt * 64 + jl * 4;
        const bf16* gp = gdhhP + (size_t)(gcol >> 7) * 16384
                       + (size_t)row * 128 + (gcol & 127);
        float g0 = 0.f, g1 = 0.f, g2 = 0.f, g3 = 0.f;
#pragma unroll
        for (int z = 0; z < 4; ++z) {
            bf16x4 v = *(const bf16x4*)(gp + (size_t)z * 524288);
            g0 += (float)v[0]; g1 += (float)v[1]; g2 += (float)v[2]; g3 += (float)v[3];
        }
        float gi = cr[0] + g0 + b_ihd[J]        + b_hhd[J];
        float gf = cr[1] + g1 + b_ihd[1024 + J] + b_hhd[1024 + J];
        float gg = cr[2] + g2 + b_ihd[2048 + J] + b_hhd[2048 + J];
        float go = cr[3] + g3 + b_ihd[3072 + J] + b_hhd[3072 + J];
        int ci = row * 1024 + J;
        float cn = sigf(gf) * c_dec[ci] + sigf(gi) * tanhf(gg);
        c_dec[ci] = cn;
        hdec[ci] = (bf16)(sigf(go) * tanhf(cn));
    }
}

// ---------------- init + weight packing ----------------
#define PBL (B_ * 4096)
#define PBH (B_ * 1024)

__global__ void init_k(const float* __restrict__ x, const float* __restrict__ c0,
                       const float* __restrict__ h0e, const float* __restrict__ h0d,
                       float* __restrict__ c_t, float* __restrict__ c_enc,
                       float* __restrict__ c_dec, bf16* __restrict__ negs,
                       bf16* __restrict__ henc, bf16* __restrict__ hdec,
                       bf16* __restrict__ x_bf) {
    int i = blockIdx.x * 256 + threadIdx.x;
    if (i >= PBL) return;
    int n = i & 4095;
    float c = c0[n];
    c_t[i] = c;
    negs[i] = (bf16)(-sigf(c));
    x_bf[i] = (bf16)x[i];
    if (i < PBH) {
        int j = i & 1023;
        c_enc[i] = 0.f;
        c_dec[i] = 0.f;
        henc[i] = (bf16)h0e[j];
        hdec[i] = (bf16)h0d[j];
    }
}

__device__ __forceinline__ bf16x8 cvt8(const float* s) {
    float4 a = *(const float4*)s, b = *(const float4*)(s + 4);
    bf16x8 v = { (bf16)a.x, (bf16)a.y, (bf16)a.z, (bf16)a.w,
                 (bf16)b.x, (bf16)b.y, (bf16)b.z, (bf16)b.w };
    return v;
}

// np = 4j+g <-> n = g*1024+j.  Wxh[np][4096], Wsum[np][4096],
// Wd_e[np][1024], We_e[np][1024].
__global__ void conv_es_k(const float* __restrict__ Wih, const float* __restrict__ Whh,
                          bf16* __restrict__ wxh, bf16* __restrict__ wsum,
                          bf16* __restrict__ wde, bf16* __restrict__ wee) {
    int id = blockIdx.x * 256 + threadIdx.x;
    if (id >= 4096 * 768) return;
    int np = id / 768, c = (id - np * 768) * 8;
    int n = ((np & 3) << 10) + (np >> 2);
    if (c < 4096) {
        const float* sx = Wih + (size_t)n * 9216 + c;
        const float* sh = sx + 4096;
        float4 a = *(const float4*)sh, b = *(const float4*)(sh + 4);
        float4 e = *(const float4*)sx, f = *(const float4*)(sx + 4);
        bf16x8 vh = { (bf16)a.x, (bf16)a.y, (bf16)a.z, (bf16)a.w,
                      (bf16)b.x, (bf16)b.y, (bf16)b.z, (bf16)b.w };
        bf16x8 vs = { (bf16)(a.x + e.x), (bf16)(a.y + e.y), (bf16)(a.z + e.z), (bf16)(a.w + e.w),
                      (bf16)(b.x + f.x), (bf16)(b.y + f.y), (bf16)(b.z + f.z), (bf16)(b.w + f.w) };
        *(bf16x8*)(wxh  + (size_t)np * 4096 + c) = vh;
        *(bf16x8*)(wsum + (size_t)np * 4096 + c) = vs;
    } else if (c < 5120) {
        *(bf16x8*)(wde + (size_t)np * 1024 + (c - 4096)) =
            cvt8(Wih + (size_t)n * 9216 + 8192 + (c - 4096));
    } else {
        *(bf16x8*)(wee + (size_t)np * 1024 + (c - 5120)) =
            cvt8(Whh + (size_t)n * 1024 + (c - 5120));
    }
}

__global__ void conv_dec_k(const float* __restrict__ Wih, const float* __restrict__ Whh,
                           bf16* __restrict__ wdz, bf16* __restrict__ wdh) {
    int id = blockIdx.x * 256 + threadIdx.x;
    if (id >= 4096 * 160) return;
    int np = id / 160, c = (id - np * 160) * 8;
    int n = ((np & 3) << 10) + (np >> 2);
    if (c < 256)
        *(bf16x8*)(wdz + (size_t)np * 256 + c) = cvt8(Wih + (size_t)n * 256 + c);
    else
        *(bf16x8*)(wdh + (size_t)np * 1024 + (c - 256)) =
            cvt8(Whh + (size_t)n * 1024 + (c - 256));
}

__global__ void conv_ms_k(const float* __restrict__ Wmu, const float* __restrict__ Wsig,
                          bf16* __restrict__ dst) {
    int id = blockIdx.x * 256 + threadIdx.x;
    if (id >= 512 * 128) return;
    int np = id >> 7, c = (id & 127) * 8;
    int zi = np >> 1;
    const float* src = ((np & 1) ? Wsig : Wmu) + (size_t)zi * 1024 + c;
    *(bf16x8*)(dst + (size_t)np * 1024 + c) = cvt8(src);
}

__global__ void conv_wr_k(const float* __restrict__ Wwr, bf16* __restrict__ dst) {
    int id = blockIdx.x * 256 + threadIdx.x;
    if (id >= 4096 * 128) return;
    *(bf16x8*)(dst + (size_t)id * 8) = cvt8(Wwr + (size_t)id * 8);
}

// ---------------- launch ----------------
extern "C" void kernel_launch(void* const* d_in, const int* in_sizes, int n_in,
                              void* d_out, int out_size, void* d_ws, size_t ws_size,
                              hipStream_t stream) {
    const float* x      = (const float*)d_in[0];
    const float* eps    = (const float*)d_in[1];
    const float* c0     = (const float*)d_in[2];
    const float* h0e    = (const float*)d_in[3];
    const float* h0d    = (const float*)d_in[4];
    const float* W_ih_e = (const float*)d_in[5];
    const float* b_ih_e = (const float*)d_in[6];
    const float* W_hh_e = (const float*)d_in[7];
    const float* b_hh_e = (const float*)d_in[8];
    const float* W_mu   = (const float*)d_in[9];
    const float* b_mu   = (const float*)d_in[10];
    const float* W_sig  = (const float*)d_in[11];
    const float* b_sig  = (const float*)d_in[12];
    const float* W_ih_d = (const float*)d_in[13];
    const float* b_ih_d = (const float*)d_in[14];
    const float* W_hh_d = (const float*)d_in[15];
    const float* b_hh_d = (const float*)d_in[16];
    const float* W_wr   = (const float*)d_in[17];
    const float* b_wr   = (const float*)d_in[18];
    float* out = (float*)d_out;

    float* f = (float*)d_ws;
    float* c_t    = f; f += 524288;
    float* base   = f; f += 524288;
    float* c_enc  = f; f += 131072;
    float* c_dec  = f; f += 131072;
    bf16* bp     = (bf16*)f;
    bf16* part   = bp; bp += (size_t)16 * 32 * 16384;   // 16 MB bf16 slices
    bf16* hdP    = bp; bp += (size_t)4 * 32 * 16384;
    bf16* heP    = bp; bp += (size_t)4 * 32 * 16384;
    bf16* gdhhP  = bp; bp += (size_t)4 * 32 * 16384;
    bf16* negs   = bp; bp += (size_t)B_ * 4096;
    bf16* henc   = bp; bp += (size_t)B_ * 1024;
    bf16* hdec   = bp; bp += (size_t)B_ * 1024;
    bf16* zbf    = bp; bp += (size_t)B_ * 256;
    bf16* x_bf   = bp; bp += (size_t)B_ * 4096;
    bf16* Wxh    = bp; bp += (size_t)4096 * 4096;
    bf16* Wsum   = bp; bp += (size_t)4096 * 4096;
    bf16* Wd_e   = bp; bp += (size_t)4096 * 1024;
    bf16* We_e   = bp; bp += (size_t)4096 * 1024;
    bf16* Wdz    = bp; bp += (size_t)4096 * 256;
    bf16* Wdh    = bp; bp += (size_t)4096 * 1024;
    bf16* Wms    = bp; bp += (size_t)512 * 1024;
    bf16* Wwr    = bp; bp += (size_t)4096 * 1024;

    dim3 blk(256);

    init_k<<<(PBL + 255) / 256, blk, 0, stream>>>(x, c0, h0e, h0d, c_t, c_enc, c_dec,
                                                  negs, henc, hdec, x_bf);
    conv_es_k<<<(4096 * 768 + 255) / 256, blk, 0, stream>>>(W_ih_e, W_hh_e,
                                                            Wxh, Wsum, Wd_e, We_e);
    conv_dec_k<<<(4096 * 160 + 255) / 256, blk, 0, stream>>>(W_ih_d, W_hh_d, Wdz, Wdh);
    conv_ms_k<<<(512 * 128 + 255) / 256, blk, 0, stream>>>(W_mu, W_sig, Wms);
    conv_wr_k<<<(4096 * 128 + 255) / 256, blk, 0, stream>>>(W_wr, Wwr);

    // base = b_ih_e + b_hh_e + x @ Wsum^T  (gate-permuted), z=16
    gemm_bp<<<dim3(32, 16), blk, 0, stream>>>(x_bf, 4096, Wsum, 4096, 256, part);
    fin0_k<<<dim3(512), blk, 0, stream>>>(part, base, b_ih_e, b_hh_e);

    // preloop: hdP/heP/gdhhP from initial h_dec, h_enc (roles 1..3 only)
    kE_k<<<dim3(384), blk, 0, stream>>>(hdec, henc, Wwr, Wd_e, We_e, Wdh,
        c_t, negs, hdP, heP, gdhhP, b_wr, nullptr);

    for (int t = 0; t < T_; ++t) {
        // kA: negs @ Wxh^T (K=4096), z=16 -> bf16 slices (512 blocks)
        gemm_bp<<<dim3(32, 16), blk, 0, stream>>>(negs, 4096, Wxh, 4096, 256, part);
        // kB: 16 slices + base + hdP + heP -> enc LSTM -> henc
        kB_k<<<dim3(512), blk, 0, stream>>>(part, base, hdP, heP, c_enc, henc);
        // kC: mu/sigma + reparam -> zbf
        kC_k<<<dim3(16), blk, 0, stream>>>(henc, Wms, b_mu, b_sig,
                                           eps + (size_t)t * (B_ * 256), zbf);
        // kD: dec z-part + gdhh slices + LSTM -> hdec
        kD_k<<<dim3(64), blk, 0, stream>>>(zbf, Wdz, gdhhP, b_ih_d, b_hh_d, c_dec, hdec);
        // kE: role0 wr (c_t,negs,out) + roles 1-3 split-K slices for next step
        kE_k<<<dim3(416), blk, 0, stream>>>(hdec, henc, Wwr, Wd_e, We_e, Wdh,
            c_t, negs, hdP, heP, gdhhP, b_wr,
            (t == T_ - 1) ? out : nullptr);
    }
}

// Round 10
// 921.142 us; speedup vs baseline: 1.1972x; 1.1972x over previous
//
#include <hip/hip_runtime.h>

#define B_   128
#define T_   16

typedef __bf16 bf16;
typedef __bf16 bf16x8 __attribute__((ext_vector_type(8)));
typedef float f32x4 __attribute__((ext_vector_type(4)));

#define GLL(SRC, DST) __builtin_amdgcn_global_load_lds( \
    (const __attribute__((address_space(1))) void*)(SRC), \
    (__attribute__((address_space(3))) void*)(DST), 16, 0, 0)

#define MFMA __builtin_amdgcn_mfma_f32_16x16x32_bf16
#define SLICE 524288   // 128*4096 fp32 per partial slice

__device__ __forceinline__ float sigf(float x) { return 1.f / (1.f + expf(-x)); }

// ---------------------------------------------------------------------------
// R2-proven 64x64-tile GEMM core: BK=64, double-buffered 32KB LDS, 4 waves
// each 32x32 output. 4+ blocks/CU occupancy.
// ---------------------------------------------------------------------------
__device__ __forceinline__ void core64(
    bf16 (&As)[2][4096], bf16 (&Bs)[2][4096],
    const bf16* __restrict__ Ab, int lda,
    const bf16* __restrict__ Wb, int ldw,
    int nk, f32x4 (&acc)[4])
{
    const int tid = threadIdx.x, lane = tid & 63, wave = tid >> 6;
    const int srow = lane >> 3;
    const int scol = ((lane & 7) ^ srow) << 3;     // pre-swizzled source col
    const int wr = wave & 1, wc = wave >> 1;
    const int ln = lane & 15;
    const int rA0 = wr * 32 + ln;
    const int rB0 = wc * 32 + ln;
    const int swz = (lane & 7) << 4;
    const int kq  = (lane >> 4) << 4;

    auto stage = [&](int b, int koff) {
        int c0 = wave, c1 = wave + 4;
        int ra0 = c0 * 8 + srow, ra1 = c1 * 8 + srow;
        GLL(Ab + (size_t)ra0 * lda + koff + scol, &As[b][c0 * 512]);
        GLL(Ab + (size_t)ra1 * lda + koff + scol, &As[b][c1 * 512]);
        GLL(Wb + (size_t)ra0 * ldw + koff + scol, &Bs[b][c0 * 512]);
        GLL(Wb + (size_t)ra1 * ldw + koff + scol, &Bs[b][c1 * 512]);
    };

    stage(0, 0);
    int bq = 0;
    for (int it = 0; it < nk; ++it) {
        __syncthreads();
        if (it + 1 < nk) stage(bq ^ 1, (it + 1) << 6);
        const bf16* as = As[bq];
        const bf16* bs = Bs[bq];
#pragma unroll
        for (int k2 = 0; k2 < 2; ++k2) {
            const int co = (((k2 << 6) | kq) ^ swz) >> 1;
            bf16x8 a0 = *(const bf16x8*)&as[rA0 * 64 + co];
            bf16x8 a1 = *(const bf16x8*)&as[(rA0 + 16) * 64 + co];
            bf16x8 b0 = *(const bf16x8*)&bs[rB0 * 64 + co];
            bf16x8 b1 = *(const bf16x8*)&bs[(rB0 + 16) * 64 + co];
            acc[0] = MFMA(a0, b0, acc[0], 0, 0, 0);
            acc[1] = MFMA(a0, b1, acc[1], 0, 0, 0);
            acc[2] = MFMA(a1, b0, acc[2], 0, 0, 0);
            acc[3] = MFMA(a1, b1, acc[3], 0, 0, 0);
        }
        bq ^= 1;
    }
}

__device__ __forceinline__ void store64(float* __restrict__ P, int bm, int bn,
                                        f32x4 (&acc)[4])
{
    const int lane = threadIdx.x & 63, wave = threadIdx.x >> 6;
    const int wr = wave & 1, wc = wave >> 1;
    const int ln = lane & 15, q = lane >> 4;
    const int row0 = bm + wr * 32 + q * 4;
    const int col0 = bn + wc * 32 + ln;
#pragma unroll
    for (int r = 0; r < 4; ++r) {
        P[(size_t)(row0 + r) * 4096 + col0]           = acc[0][r];
        P[(size_t)(row0 + r) * 4096 + col0 + 16]      = acc[1][r];
        P[(size_t)(row0 + 16 + r) * 4096 + col0]      = acc[2][r];
        P[(size_t)(row0 + 16 + r) * 4096 + col0 + 16] = acc[3][r];
    }
}

// generic split-K GEMM -> fp32 slices. grid (64 nt, 2 mt, z)
__global__ __launch_bounds__(256) void gemm64_k(
    const bf16* __restrict__ A, int lda,
    const bf16* __restrict__ W, int ldw, int Kc,
    float* __restrict__ P)
{
    __shared__ bf16 As[2][4096], Bs[2][4096];
    const int nt = blockIdx.x, mt = blockIdx.y, zz = blockIdx.z;
    f32x4 acc[4];
#pragma unroll
    for (int i = 0; i < 4; ++i) acc[i] = (f32x4){0.f, 0.f, 0.f, 0.f};
    const bf16* Ab = A + (size_t)mt * 64 * lda + (size_t)zz * Kc;
    const bf16* Wb = W + (size_t)nt * 64 * ldw + (size_t)zz * Kc;
    core64(As, Bs, Ab, lda, Wb, ldw, Kc >> 6, acc);
    store64(P + (size_t)zz * SLICE, mt * 64, nt * 64, acc);
}

// ---------------------------------------------------------------------------
// kE: end-of-step combined GEMMs. grid (64, 2, 5) [loop] / (64,2,3)+zoff=2 [pre]
//  zz 0-1: wr   : hdec @ Wwr        K=1024 z=2 -> wrP slices 0-1
//  zz 2-3: hdhe : [hdec|henc]@Wcat  K=2048 z=2 -> encP slices 4-5
//  zz 4  : gdhh : hdec @ Wdh        K=1024 z=1 -> decP slice 1
// ---------------------------------------------------------------------------
__global__ __launch_bounds__(256) void kE_k(
    const bf16* __restrict__ hh,   const bf16* __restrict__ Wwr,
    const bf16* __restrict__ Wcat, const bf16* __restrict__ Wdh,
    float* __restrict__ wrP, float* __restrict__ encP, float* __restrict__ decP,
    int zoff)
{
    __shared__ bf16 As[2][4096], Bs[2][4096];
    const int nt = blockIdx.x, mt = blockIdx.y, zz = blockIdx.z + zoff;
    f32x4 acc[4];
#pragma unroll
    for (int i = 0; i < 4; ++i) acc[i] = (f32x4){0.f, 0.f, 0.f, 0.f};

    const bf16* Ab;
    const bf16* Wb;
    int ldw, nk;
    float* P;
    if (zz < 2) {
        Ab = hh + (size_t)mt * 64 * 2048 + zz * 512;
        Wb = Wwr + (size_t)nt * 64 * 1024 + zz * 512;
        ldw = 1024; nk = 8; P = wrP + (size_t)zz * SLICE;
    } else if (zz < 4) {
        int s = zz - 2;
        Ab = hh + (size_t)mt * 64 * 2048 + s * 1024;
        Wb = Wcat + (size_t)nt * 64 * 2048 + s * 1024;
        ldw = 2048; nk = 16; P = encP + (size_t)(4 + s) * SLICE;
    } else {
        Ab = hh + (size_t)mt * 64 * 2048;
        Wb = Wdh + (size_t)nt * 64 * 1024;
        ldw = 1024; nk = 16; P = decP + SLICE;
    }
    core64(As, Bs, Ab, 2048, Wb, ldw, nk, acc);
    store64(P, mt * 64, nt * 64, acc);
}

// ---------------------------------------------------------------------------
// consumers (grid 512 x 256, one gate-quad / element-quad per thread)
// ---------------------------------------------------------------------------
__global__ __launch_bounds__(256) void fin0_k(
    const float* __restrict__ P, float* __restrict__ base,
    const float* __restrict__ b1, const float* __restrict__ b2)
{
    const int i = blockIdx.x * 256 + threadIdx.x;     // 0..131071
    const int row = i >> 10, j = i & 1023;
    const size_t off = (size_t)row * 4096 + (j << 2);
    float s0 = 0.f, s1 = 0.f, s2 = 0.f, s3 = 0.f;
#pragma unroll
    for (int z = 0; z < 4; ++z) {
        float4 p = *(const float4*)(P + (size_t)z * SLICE + off);
        s0 += p.x; s1 += p.y; s2 += p.z; s3 += p.w;
    }
    base[off + 0] = s0 + b1[j]        + b2[j];
    base[off + 1] = s1 + b1[1024 + j] + b2[1024 + j];
    base[off + 2] = s2 + b1[2048 + j] + b2[2048 + j];
    base[off + 3] = s3 + b1[3072 + j] + b2[3072 + j];
}

// kB: sum encP slices 0-5 + base -> enc LSTM -> henc (hh[1024+j])
__global__ __launch_bounds__(256) void kB_k(
    const float* __restrict__ encP, const float* __restrict__ base,
    float* __restrict__ c_enc, bf16* __restrict__ hh)
{
    const int i = blockIdx.x * 256 + threadIdx.x;
    const int row = i >> 10, j = i & 1023;
    const size_t off = (size_t)row * 4096 + (j << 2);
    float s0 = 0.f, s1 = 0.f, s2 = 0.f, s3 = 0.f;
#pragma unroll
    for (int z = 0; z < 6; ++z) {
        float4 p = *(const float4*)(encP + (size_t)z * SLICE + off);
        s0 += p.x; s1 += p.y; s2 += p.z; s3 += p.w;
    }
    float4 bb = *(const float4*)(base + off);
    float gi = s0 + bb.x, gf = s1 + bb.y, gg = s2 + bb.z, go = s3 + bb.w;
    float cn = sigf(gf) * c_enc[i] + sigf(gi) * tanhf(gg);
    c_enc[i] = cn;
    hh[(size_t)row * 2048 + 1024 + j] = (bf16)(sigf(go) * tanhf(cn));
}

// kD2: sum decP slices 0-1 + dec biases -> dec LSTM -> hdec (hh[j])
__global__ __launch_bounds__(256) void kD2_k(
    const float* __restrict__ decP,
    const float* __restrict__ b_ihd, const float* __restrict__ b_hhd,
    float* __restrict__ c_dec, bf16* __restrict__ hh)
{
    const int i = blockIdx.x * 256 + threadIdx.x;
    const int row = i >> 10, j = i & 1023;
    const size_t off = (size_t)row * 4096 + (j << 2);
    float4 p0 = *(const float4*)(decP + off);
    float4 p1 = *(const float4*)(decP + SLICE + off);
    float gi = p0.x + p1.x + b_ihd[j]        + b_hhd[j];
    float gf = p0.y + p1.y + b_ihd[1024 + j] + b_hhd[1024 + j];
    float gg = p0.z + p1.z + b_ihd[2048 + j] + b_hhd[2048 + j];
    float go = p0.w + p1.w + b_ihd[3072 + j] + b_hhd[3072 + j];
    float cn = sigf(gf) * c_dec[i] + sigf(gi) * tanhf(gg);
    c_dec[i] = cn;
    hh[(size_t)row * 2048 + j] = (bf16)(sigf(go) * tanhf(cn));
}

// kF: c_t += wrP0+wrP1 + b_wr -> negs; optional out
__global__ __launch_bounds__(256) void kF_k(
    const float* __restrict__ wrP, const float* __restrict__ b_wr,
    float* __restrict__ c_t, bf16* __restrict__ negs, float* __restrict__ outp)
{
    const int qi = blockIdx.x * 256 + threadIdx.x;    // 0..131071
    const int row = qi >> 10, cq = qi & 1023;
    const size_t off = (size_t)row * 4096 + (cq << 2);
    float4 p0 = *(const float4*)(wrP + off);
    float4 p1 = *(const float4*)(wrP + SLICE + off);
    float4 cv = *(const float4*)(c_t + off);
    float4 bw = *(const float4*)(b_wr + (cq << 2));
    float v0 = cv.x + p0.x + p1.x + bw.x;
    float v1 = cv.y + p0.y + p1.y + bw.y;
    float v2 = cv.z + p0.z + p1.z + bw.z;
    float v3 = cv.w + p0.w + p1.w + bw.w;
    *(float4*)(c_t + off) = make_float4(v0, v1, v2, v3);
    negs[off + 0] = (bf16)(-sigf(v0));
    negs[off + 1] = (bf16)(-sigf(v1));
    negs[off + 2] = (bf16)(-sigf(v2));
    negs[off + 3] = (bf16)(-sigf(v3));
    if (outp)
        *(float4*)(outp + off) = make_float4(sigf(v0), sigf(v1), sigf(v2), sigf(v3));
}

// ---------------------------------------------------------------------------
// kC: mu/sigma GEMM (128x32 tile, K=1024 as 4x256 chunks) + reparam. grid 16.
// A = henc rows of hh (lda 2048, offset 1024). Proven in R6/R8.
// ---------------------------------------------------------------------------
struct SmemG32 {
    bf16 As[4][128][64];   // 64 KB
    bf16 Ws[4][32][64];    // 16 KB
};

__global__ __launch_bounds__(256) void kC_k(
    const bf16* __restrict__ hh, const bf16* __restrict__ Wms,
    const float* __restrict__ b_mu, const float* __restrict__ b_sig,
    const float* __restrict__ eps_t, bf16* __restrict__ zbf)
{
    __shared__ SmemG32 sm;
    const int nt = blockIdx.x;
    const int tid = threadIdx.x, lane = tid & 63, wave = tid >> 6;
    const int srow = lane >> 3, scol = ((lane & 7) ^ srow) << 3;
    const int ln = lane & 15, kq = (lane >> 4) << 4;
    const int swz = (lane & 7) << 4;
    const int rA = wave * 32 + ln;
    const bf16* Wb = Wms + (size_t)nt * 32 * 1024;
    const bf16* Ab = hh + 1024;

    f32x4 acc[2][2];
#pragma unroll
    for (int m = 0; m < 2; ++m)
#pragma unroll
        for (int n = 0; n < 2; ++n) acc[m][n] = (f32x4){0.f, 0.f, 0.f, 0.f};

    for (int it = 0; it < 4; ++it) {
        if (it) __syncthreads();
        const int koff = it * 256;
#pragma unroll
        for (int kc = 0; kc < 4; ++kc) {
            const int kg = koff + kc * 64 + scol;
#pragma unroll
            for (int i = 0; i < 4; ++i) {
                int rb = i * 32 + wave * 8;
                GLL(Ab + (size_t)(rb + srow) * 2048 + kg, &sm.As[kc][rb][0]);
            }
            GLL(Wb + (size_t)(wave * 8 + srow) * 1024 + kg, &sm.Ws[kc][wave * 8][0]);
        }
        __syncthreads();
#pragma unroll
        for (int kc = 0; kc < 4; ++kc)
#pragma unroll
            for (int k2 = 0; k2 < 2; ++k2) {
                const int co = (((k2 << 6) | kq) ^ swz) >> 1;
                bf16x8 a0 = *(const bf16x8*)&sm.As[kc][rA][co];
                bf16x8 a1 = *(const bf16x8*)&sm.As[kc][rA + 16][co];
                bf16x8 b0 = *(const bf16x8*)&sm.Ws[kc][ln][co];
                bf16x8 b1 = *(const bf16x8*)&sm.Ws[kc][ln + 16][co];
                acc[0][0] = MFMA(a0, b0, acc[0][0], 0, 0, 0);
                acc[0][1] = MFMA(a0, b1, acc[0][1], 0, 0, 0);
                acc[1][0] = MFMA(a1, b0, acc[1][0], 0, 0, 0);
                acc[1][1] = MFMA(a1, b1, acc[1][1], 0, 0, 0);
            }
    }
    __syncthreads();

    float* Cl = (float*)&sm;
    const int q = lane >> 4;
#pragma unroll
    for (int f = 0; f < 2; ++f)
#pragma unroll
        for (int n = 0; n < 2; ++n)
#pragma unroll
            for (int r = 0; r < 4; ++r)
                Cl[(wave * 32 + f * 16 + q * 4 + r) * 33 + n * 16 + ln] = acc[f][n][r];
    __syncthreads();

#pragma unroll
    for (int it = 0; it < 8; ++it) {
        int li = it * 256 + tid;
        int row = li >> 4, zl = li & 15;
        int zi = nt * 16 + zl;
        float mu = Cl[row * 33 + zl * 2]     + b_mu[zi];
        float ls = Cl[row * 33 + zl * 2 + 1] + b_sig[zi];
        float z = eps_t[row * 256 + zi] * expf(ls) + mu;
        zbf[(size_t)row * 256 + zi] = (bf16)z;
    }
}

// ---------------- init + weight packing ----------------
#define PBL (B_ * 4096)
#define PBH (B_ * 1024)

__global__ void init_k(const float* __restrict__ x, const float* __restrict__ c0,
                       const float* __restrict__ h0e, const float* __restrict__ h0d,
                       float* __restrict__ c_t, float* __restrict__ c_enc,
                       float* __restrict__ c_dec, bf16* __restrict__ negs,
                       bf16* __restrict__ hh, bf16* __restrict__ x_bf) {
    int i = blockIdx.x * 256 + threadIdx.x;
    if (i >= PBL) return;
    int n = i & 4095;
    float c = c0[n];
    c_t[i] = c;
    negs[i] = (bf16)(-sigf(c));
    x_bf[i] = (bf16)x[i];
    if (i < PBH) {
        int row = i >> 10, j = i & 1023;
        c_enc[i] = 0.f;
        c_dec[i] = 0.f;
        hh[(size_t)row * 2048 + j]        = (bf16)h0d[j];
        hh[(size_t)row * 2048 + 1024 + j] = (bf16)h0e[j];
    }
}

__device__ __forceinline__ bf16x8 cvt8(const float* s) {
    float4 a = *(const float4*)s, b = *(const float4*)(s + 4);
    bf16x8 v = { (bf16)a.x, (bf16)a.y, (bf16)a.z, (bf16)a.w,
                 (bf16)b.x, (bf16)b.y, (bf16)b.z, (bf16)b.w };
    return v;
}

// np = 4j+g <-> n = g*1024+j.  Wxh[np][4096], Wsum[np][4096],
// Wcat[np][0..1024)=Wih(hdec), Wcat[np][1024..2048)=Whh(henc).
__global__ void conv_es_k(const float* __restrict__ Wih, const float* __restrict__ Whh,
                          bf16* __restrict__ wxh, bf16* __restrict__ wsum,
                          bf16* __restrict__ wcat) {
    int id = blockIdx.x * 256 + threadIdx.x;
    if (id >= 4096 * 768) return;
    int np = id / 768, c = (id - np * 768) * 8;
    int n = ((np & 3) << 10) + (np >> 2);
    if (c < 4096) {
        const float* sx = Wih + (size_t)n * 9216 + c;
        const float* sh = sx + 4096;
        float4 a = *(const float4*)sh, b = *(const float4*)(sh + 4);
        float4 e = *(const float4*)sx, f = *(const float4*)(sx + 4);
        bf16x8 vh = { (bf16)a.x, (bf16)a.y, (bf16)a.z, (bf16)a.w,
                      (bf16)b.x, (bf16)b.y, (bf16)b.z, (bf16)b.w };
        bf16x8 vs = { (bf16)(a.x + e.x), (bf16)(a.y + e.y), (bf16)(a.z + e.z), (bf16)(a.w + e.w),
                      (bf16)(b.x + f.x), (bf16)(b.y + f.y), (bf16)(b.z + f.z), (bf16)(b.w + f.w) };
        *(bf16x8*)(wxh  + (size_t)np * 4096 + c) = vh;
        *(bf16x8*)(wsum + (size_t)np * 4096 + c) = vs;
    } else if (c < 5120) {
        *(bf16x8*)(wcat + (size_t)np * 2048 + (c - 4096)) =
            cvt8(Wih + (size_t)n * 9216 + 8192 + (c - 4096));
    } else {
        *(bf16x8*)(wcat + (size_t)np * 2048 + 1024 + (c - 5120)) =
            cvt8(Whh + (size_t)n * 1024 + (c - 5120));
    }
}

__global__ void conv_dec_k(const float* __restrict__ Wih, const float* __restrict__ Whh,
                           bf16* __restrict__ wdz, bf16* __restrict__ wdh) {
    int id = blockIdx.x * 256 + threadIdx.x;
    if (id >= 4096 * 160) return;
    int np = id / 160, c = (id - np * 160) * 8;
    int n = ((np & 3) << 10) + (np >> 2);
    if (c < 256)
        *(bf16x8*)(wdz + (size_t)np * 256 + c) = cvt8(Wih + (size_t)n * 256 + c);
    else
        *(bf16x8*)(wdh + (size_t)np * 1024 + (c - 256)) =
            cvt8(Whh + (size_t)n * 1024 + (c - 256));
}

// Wms[np][k]: np = 2*zi + s; s=0 -> Wmu[zi], s=1 -> Wsig[zi]
__global__ void conv_ms_k(const float* __restrict__ Wmu, const float* __restrict__ Wsig,
                          bf16* __restrict__ dst) {
    int id = blockIdx.x * 256 + threadIdx.x;
    if (id >= 512 * 128) return;
    int np = id >> 7, c = (id & 127) * 8;
    int zi = np >> 1;
    const float* src = ((np & 1) ? Wsig : Wmu) + (size_t)zi * 1024 + c;
    *(bf16x8*)(dst + (size_t)np * 1024 + c) = cvt8(src);
}

__global__ void conv_wr_k(const float* __restrict__ Wwr, bf16* __restrict__ dst) {
    int id = blockIdx.x * 256 + threadIdx.x;
    if (id >= 4096 * 128) return;
    *(bf16x8*)(dst + (size_t)id * 8) = cvt8(Wwr + (size_t)id * 8);
}

// ---------------- launch ----------------
extern "C" void kernel_launch(void* const* d_in, const int* in_sizes, int n_in,
                              void* d_out, int out_size, void* d_ws, size_t ws_size,
                              hipStream_t stream) {
    const float* x      = (const float*)d_in[0];
    const float* eps    = (const float*)d_in[1];
    const float* c0     = (const float*)d_in[2];
    const float* h0e    = (const float*)d_in[3];
    const float* h0d    = (const float*)d_in[4];
    const float* W_ih_e = (const float*)d_in[5];
    const float* b_ih_e = (const float*)d_in[6];
    const float* W_hh_e = (const float*)d_in[7];
    const float* b_hh_e = (const float*)d_in[8];
    const float* W_mu   = (const float*)d_in[9];
    const float* b_mu   = (const float*)d_in[10];
    const float* W_sig  = (const float*)d_in[11];
    const float* b_sig  = (const float*)d_in[12];
    const float* W_ih_d = (const float*)d_in[13];
    const float* b_ih_d = (const float*)d_in[14];
    const float* W_hh_d = (const float*)d_in[15];
    const float* b_hh_d = (const float*)d_in[16];
    const float* W_wr   = (const float*)d_in[17];
    const float* b_wr   = (const float*)d_in[18];
    float* out = (float*)d_out;

    float* f = (float*)d_ws;
    float* c_t   = f; f += SLICE;
    float* base  = f; f += SLICE;
    float* encP  = f; f += (size_t)6 * SLICE;   // slices 0-3: kA; 4-5: hdhe (kE)
    float* decP  = f; f += (size_t)2 * SLICE;   // 0: dec-z; 1: gdhh (kE)
    float* wrP   = f; f += (size_t)2 * SLICE;
    float* c_enc = f; f += 131072;
    float* c_dec = f; f += 131072;
    bf16* bp    = (bf16*)f;
    bf16* negs  = bp; bp += (size_t)B_ * 4096;
    bf16* hh    = bp; bp += (size_t)B_ * 2048;  // [hdec | henc] per row
    bf16* zbf   = bp; bp += (size_t)B_ * 256;
    bf16* x_bf  = bp; bp += (size_t)B_ * 4096;
    bf16* Wxh   = bp; bp += (size_t)4096 * 4096;
    bf16* Wsum  = bp; bp += (size_t)4096 * 4096;
    bf16* Wcat  = bp; bp += (size_t)4096 * 2048;
    bf16* Wdz   = bp; bp += (size_t)4096 * 256;
    bf16* Wdh   = bp; bp += (size_t)4096 * 1024;
    bf16* Wms   = bp; bp += (size_t)512 * 1024;
    bf16* Wwr   = bp; bp += (size_t)4096 * 1024;

    dim3 blk(256);

    init_k<<<(PBL + 255) / 256, blk, 0, stream>>>(x, c0, h0e, h0d, c_t, c_enc, c_dec,
                                                  negs, hh, x_bf);
    conv_es_k<<<(4096 * 768 + 255) / 256, blk, 0, stream>>>(W_ih_e, W_hh_e,
                                                            Wxh, Wsum, Wcat);
    conv_dec_k<<<(4096 * 160 + 255) / 256, blk, 0, stream>>>(W_ih_d, W_hh_d, Wdz, Wdh);
    conv_ms_k<<<(512 * 128 + 255) / 256, blk, 0, stream>>>(W_mu, W_sig, Wms);
    conv_wr_k<<<(4096 * 128 + 255) / 256, blk, 0, stream>>>(W_wr, Wwr);

    // base = b_ih_e + b_hh_e + x @ Wsum^T  (gate-interleaved cols), z=4
    gemm64_k<<<dim3(64, 2, 4), blk, 0, stream>>>(x_bf, 4096, Wsum, 4096, 1024, encP);
    fin0_k<<<dim3(512), blk, 0, stream>>>(encP, base, b_ih_e, b_hh_e);

    // preloop: hdhe (encP 4-5) + gdhh (decP 1) from initial hh
    kE_k<<<dim3(64, 2, 3), blk, 0, stream>>>(hh, Wwr, Wcat, Wdh, wrP, encP, decP, 2);

    for (int t = 0; t < T_; ++t) {
        // kA: negs @ Wxh^T (K=4096), z=4 -> encP slices 0-3 (512 blocks, 4/CU)
        gemm64_k<<<dim3(64, 2, 4), blk, 0, stream>>>(negs, 4096, Wxh, 4096, 1024, encP);
        // kB: sum 6 slices + base -> enc LSTM -> henc
        kB_k<<<dim3(512), blk, 0, stream>>>(encP, base, c_enc, hh);
        // kC: mu/sigma + reparam -> zbf
        kC_k<<<dim3(16), blk, 0, stream>>>(hh, Wms, b_mu, b_sig,
                                           eps + (size_t)t * (B_ * 256), zbf);
        // kD1: dec z-part: zbf @ Wdz^T (K=256) -> decP slice 0
        gemm64_k<<<dim3(64, 2, 1), blk, 0, stream>>>(zbf, 256, Wdz, 256, 256, decP);
        // kD2: dec LSTM (slices 0-1 + biases) -> hdec
        kD2_k<<<dim3(512), blk, 0, stream>>>(decP, b_ih_d, b_hh_d, c_dec, hh);
        // kE: wr (z=2) + hdhe (z=2) + gdhh (z=1) in one launch (640 blocks)
        kE_k<<<dim3(64, 2, 5), blk, 0, stream>>>(hh, Wwr, Wcat, Wdh, wrP, encP, decP, 0);
        // kF: c_t += wr + b_wr -> negs (+ out at last step)
        kF_k<<<dim3(512), blk, 0, stream>>>(wrP, b_wr, c_t, negs,
                                            (t == T_ - 1) ? out : nullptr);
    }
}

// Round 11
// 837.222 us; speedup vs baseline: 1.3172x; 1.1002x over previous
//
#include <hip/hip_runtime.h>

#define B_   128
#define T_   16

typedef __bf16 bf16;
typedef __bf16 bf16x4 __attribute__((ext_vector_type(4)));
typedef __bf16 bf16x8 __attribute__((ext_vector_type(8)));
typedef float f32x4 __attribute__((ext_vector_type(4)));

#define GLL(SRC, DST) __builtin_amdgcn_global_load_lds( \
    (const __attribute__((address_space(1))) void*)(SRC), \
    (__attribute__((address_space(3))) void*)(DST), 16, 0, 0)

#define MFMA __builtin_amdgcn_mfma_f32_16x16x32_bf16
#define SLICE 524288   // 128*4096 elements per partial slice

__device__ __forceinline__ float sigf(float x) { return 1.f / (1.f + expf(-x)); }

// ---------------------------------------------------------------------------
// R2/R10-proven 64x64-tile GEMM core: BK=64, dbuf 32KB LDS, 4 waves x 32x32.
// ---------------------------------------------------------------------------
__device__ __forceinline__ void core64(
    bf16 (&As)[2][4096], bf16 (&Bs)[2][4096],
    const bf16* __restrict__ Ab, int lda,
    const bf16* __restrict__ Wb, int ldw,
    int nk, f32x4 (&acc)[4])
{
    const int tid = threadIdx.x, lane = tid & 63, wave = tid >> 6;
    const int srow = lane >> 3;
    const int scol = ((lane & 7) ^ srow) << 3;     // pre-swizzled source col
    const int wr = wave & 1, wc = wave >> 1;
    const int ln = lane & 15;
    const int rA0 = wr * 32 + ln;
    const int rB0 = wc * 32 + ln;
    const int swz = (lane & 7) << 4;
    const int kq  = (lane >> 4) << 4;

    auto stage = [&](int b, int koff) {
        int c0 = wave, c1 = wave + 4;
        int ra0 = c0 * 8 + srow, ra1 = c1 * 8 + srow;
        GLL(Ab + (size_t)ra0 * lda + koff + scol, &As[b][c0 * 512]);
        GLL(Ab + (size_t)ra1 * lda + koff + scol, &As[b][c1 * 512]);
        GLL(Wb + (size_t)ra0 * ldw + koff + scol, &Bs[b][c0 * 512]);
        GLL(Wb + (size_t)ra1 * ldw + koff + scol, &Bs[b][c1 * 512]);
    };

    stage(0, 0);
    int bq = 0;
    for (int it = 0; it < nk; ++it) {
        __syncthreads();
        if (it + 1 < nk) stage(bq ^ 1, (it + 1) << 6);
        const bf16* as = As[bq];
        const bf16* bs = Bs[bq];
#pragma unroll
        for (int k2 = 0; k2 < 2; ++k2) {
            const int co = (((k2 << 6) | kq) ^ swz) >> 1;
            bf16x8 a0 = *(const bf16x8*)&as[rA0 * 64 + co];
            bf16x8 a1 = *(const bf16x8*)&as[(rA0 + 16) * 64 + co];
            bf16x8 b0 = *(const bf16x8*)&bs[rB0 * 64 + co];
            bf16x8 b1 = *(const bf16x8*)&bs[(rB0 + 16) * 64 + co];
            acc[0] = MFMA(a0, b0, acc[0], 0, 0, 0);
            acc[1] = MFMA(a0, b1, acc[1], 0, 0, 0);
            acc[2] = MFMA(a1, b0, acc[2], 0, 0, 0);
            acc[3] = MFMA(a1, b1, acc[3], 0, 0, 0);
        }
        bq ^= 1;
    }
}

__device__ __forceinline__ void store64f(float* __restrict__ P, int bm, int bn,
                                         f32x4 (&acc)[4])
{
    const int lane = threadIdx.x & 63, wave = threadIdx.x >> 6;
    const int wr = wave & 1, wc = wave >> 1;
    const int ln = lane & 15, q = lane >> 4;
    const int row0 = bm + wr * 32 + q * 4;
    const int col0 = bn + wc * 32 + ln;
#pragma unroll
    for (int r = 0; r < 4; ++r) {
        P[(size_t)(row0 + r) * 4096 + col0]           = acc[0][r];
        P[(size_t)(row0 + r) * 4096 + col0 + 16]      = acc[1][r];
        P[(size_t)(row0 + 16 + r) * 4096 + col0]      = acc[2][r];
        P[(size_t)(row0 + 16 + r) * 4096 + col0 + 16] = acc[3][r];
    }
}

__device__ __forceinline__ void store64b(bf16* __restrict__ P, int bm, int bn,
                                         f32x4 (&acc)[4])
{
    const int lane = threadIdx.x & 63, wave = threadIdx.x >> 6;
    const int wr = wave & 1, wc = wave >> 1;
    const int ln = lane & 15, q = lane >> 4;
    const int row0 = bm + wr * 32 + q * 4;
    const int col0 = bn + wc * 32 + ln;
#pragma unroll
    for (int r = 0; r < 4; ++r) {
        P[(size_t)(row0 + r) * 4096 + col0]           = (bf16)acc[0][r];
        P[(size_t)(row0 + r) * 4096 + col0 + 16]      = (bf16)acc[1][r];
        P[(size_t)(row0 + 16 + r) * 4096 + col0]      = (bf16)acc[2][r];
        P[(size_t)(row0 + 16 + r) * 4096 + col0 + 16] = (bf16)acc[3][r];
    }
}

// split-K GEMM -> fp32 slices (prologue base). grid (64 nt, 2 mt, z)
__global__ __launch_bounds__(256) void gemm64_k(
    const bf16* __restrict__ A, int lda,
    const bf16* __restrict__ W, int ldw, int Kc,
    float* __restrict__ P)
{
    __shared__ bf16 As[2][4096], Bs[2][4096];
    const int nt = blockIdx.x, mt = blockIdx.y, zz = blockIdx.z;
    f32x4 acc[4];
#pragma unroll
    for (int i = 0; i < 4; ++i) acc[i] = (f32x4){0.f, 0.f, 0.f, 0.f};
    const bf16* Ab = A + (size_t)mt * 64 * lda + (size_t)zz * Kc;
    const bf16* Wb = W + (size_t)nt * 64 * ldw + (size_t)zz * Kc;
    core64(As, Bs, Ab, lda, Wb, ldw, Kc >> 6, acc);
    store64f(P + (size_t)zz * SLICE, mt * 64, nt * 64, acc);
}

// split-K GEMM -> bf16 slices (kA). grid (64 nt, 2 mt, z)
__global__ __launch_bounds__(256) void gemm64b_k(
    const bf16* __restrict__ A, int lda,
    const bf16* __restrict__ W, int ldw, int Kc,
    bf16* __restrict__ P)
{
    __shared__ bf16 As[2][4096], Bs[2][4096];
    const int nt = blockIdx.x, mt = blockIdx.y, zz = blockIdx.z;
    f32x4 acc[4];
#pragma unroll
    for (int i = 0; i < 4; ++i) acc[i] = (f32x4){0.f, 0.f, 0.f, 0.f};
    const bf16* Ab = A + (size_t)mt * 64 * lda + (size_t)zz * Kc;
    const bf16* Wb = W + (size_t)nt * 64 * ldw + (size_t)zz * Kc;
    core64(As, Bs, Ab, lda, Wb, ldw, Kc >> 6, acc);
    store64b(P + (size_t)zz * SLICE, mt * 64, nt * 64, acc);
}

// ---------------------------------------------------------------------------
// kE: end-of-step combined GEMMs, all nk=8, bf16 slices.
// grid (64, 2, 8) [loop] / (64, 2, 6) zoff=2 [preloop]
//  zz 0-1: wr   : hdec @ Wwr   (K=1024, Kc=512) -> wrP slices 0-1
//  zz 2-5: hdhe : [hdec|henc] @ Wcat (K=2048, Kc=512) -> encP slices 8-11
//  zz 6-7: gdhh : hdec @ Wdh   (K=1024, Kc=512) -> decP slices 0-1
// ---------------------------------------------------------------------------
__global__ __launch_bounds__(256) void kE_k(
    const bf16* __restrict__ hh,   const bf16* __restrict__ Wwr,
    const bf16* __restrict__ Wcat, const bf16* __restrict__ Wdh,
    bf16* __restrict__ wrP, bf16* __restrict__ encP, bf16* __restrict__ decP,
    int zoff)
{
    __shared__ bf16 As[2][4096], Bs[2][4096];
    const int nt = blockIdx.x, mt = blockIdx.y, zz = blockIdx.z + zoff;
    f32x4 acc[4];
#pragma unroll
    for (int i = 0; i < 4; ++i) acc[i] = (f32x4){0.f, 0.f, 0.f, 0.f};

    const bf16* Ab;
    const bf16* Wb;
    int ldw;
    bf16* P;
    if (zz < 2) {
        Ab = hh + (size_t)mt * 64 * 2048 + zz * 512;
        Wb = Wwr + (size_t)nt * 64 * 1024 + zz * 512;
        ldw = 1024; P = wrP + (size_t)zz * SLICE;
    } else if (zz < 6) {
        int s = zz - 2;
        Ab = hh + (size_t)mt * 64 * 2048 + s * 512;
        Wb = Wcat + (size_t)nt * 64 * 2048 + s * 512;
        ldw = 2048; P = encP + (size_t)(8 + s) * SLICE;
    } else {
        int g = zz - 6;
        Ab = hh + (size_t)mt * 64 * 2048 + g * 512;
        Wb = Wdh + (size_t)nt * 64 * 1024 + g * 512;
        ldw = 1024; P = decP + (size_t)g * SLICE;
    }
    core64(As, Bs, Ab, 2048, Wb, ldw, 8, acc);
    store64b(P, mt * 64, nt * 64, acc);
}

// ---------------------------------------------------------------------------
// consumers
// ---------------------------------------------------------------------------
// fin0: sum 4 fp32 slices + both enc biases -> base fp32. grid 512.
__global__ __launch_bounds__(256) void fin0_k(
    const float* __restrict__ P, float* __restrict__ base,
    const float* __restrict__ b1, const float* __restrict__ b2)
{
    const int i = blockIdx.x * 256 + threadIdx.x;
    const int row = i >> 10, j = i & 1023;
    const size_t off = (size_t)row * 4096 + (j << 2);
    float s0 = 0.f, s1 = 0.f, s2 = 0.f, s3 = 0.f;
#pragma unroll
    for (int z = 0; z < 4; ++z) {
        float4 p = *(const float4*)(P + (size_t)z * SLICE + off);
        s0 += p.x; s1 += p.y; s2 += p.z; s3 += p.w;
    }
    base[off + 0] = s0 + b1[j]        + b2[j];
    base[off + 1] = s1 + b1[1024 + j] + b2[1024 + j];
    base[off + 2] = s2 + b1[2048 + j] + b2[2048 + j];
    base[off + 3] = s3 + b1[3072 + j] + b2[3072 + j];
}

// kB: sum encP bf16 slices 0-11 + base -> enc LSTM -> henc (hh[1024+j]).
__global__ __launch_bounds__(256) void kB_k(
    const bf16* __restrict__ encP, const float* __restrict__ base,
    float* __restrict__ c_enc, bf16* __restrict__ hh)
{
    const int i = blockIdx.x * 256 + threadIdx.x;
    const int row = i >> 10, j = i & 1023;
    const size_t off = (size_t)row * 4096 + (j << 2);
    float s0 = 0.f, s1 = 0.f, s2 = 0.f, s3 = 0.f;
#pragma unroll
    for (int z = 0; z < 12; ++z) {
        bf16x4 p = *(const bf16x4*)(encP + (size_t)z * SLICE + off);
        s0 += (float)p[0]; s1 += (float)p[1]; s2 += (float)p[2]; s3 += (float)p[3];
    }
    float4 bb = *(const float4*)(base + off);
    float gi = s0 + bb.x, gf = s1 + bb.y, gg = s2 + bb.z, go = s3 + bb.w;
    float cn = sigf(gf) * c_enc[i] + sigf(gi) * tanhf(gg);
    c_enc[i] = cn;
    hh[(size_t)row * 2048 + 1024 + j] = (bf16)(sigf(go) * tanhf(cn));
}

// kF: c_t += wrP0+wrP1 (bf16) + b_wr -> negs; optional out
__global__ __launch_bounds__(256) void kF_k(
    const bf16* __restrict__ wrP, const float* __restrict__ b_wr,
    float* __restrict__ c_t, bf16* __restrict__ negs, float* __restrict__ outp)
{
    const int qi = blockIdx.x * 256 + threadIdx.x;
    const int row = qi >> 10, cq = qi & 1023;
    const size_t off = (size_t)row * 4096 + (cq << 2);
    bf16x4 p0 = *(const bf16x4*)(wrP + off);
    bf16x4 p1 = *(const bf16x4*)(wrP + SLICE + off);
    float4 cv = *(const float4*)(c_t + off);
    float4 bw = *(const float4*)(b_wr + (cq << 2));
    float v0 = cv.x + (float)p0[0] + (float)p1[0] + bw.x;
    float v1 = cv.y + (float)p0[1] + (float)p1[1] + bw.y;
    float v2 = cv.z + (float)p0[2] + (float)p1[2] + bw.z;
    float v3 = cv.w + (float)p0[3] + (float)p1[3] + bw.w;
    *(float4*)(c_t + off) = make_float4(v0, v1, v2, v3);
    negs[off + 0] = (bf16)(-sigf(v0));
    negs[off + 1] = (bf16)(-sigf(v1));
    negs[off + 2] = (bf16)(-sigf(v2));
    negs[off + 3] = (bf16)(-sigf(v3));
    if (outp)
        *(float4*)(outp + off) = make_float4(sigf(v0), sigf(v1), sigf(v2), sigf(v3));
}

// ---------------------------------------------------------------------------
// kC: mu/sigma GEMM (128x32 tile, K=1024 as 4x256) + reparam -> zbf. grid 16.
// ---------------------------------------------------------------------------
struct SmemG32 {
    bf16 As[4][128][64];   // 64 KB
    bf16 Ws[4][32][64];    // 16 KB
};

__global__ __launch_bounds__(256) void kC_k(
    const bf16* __restrict__ hh, const bf16* __restrict__ Wms,
    const float* __restrict__ b_mu, const float* __restrict__ b_sig,
    const float* __restrict__ eps_t, bf16* __restrict__ zbf)
{
    __shared__ SmemG32 sm;
    const int nt = blockIdx.x;
    const int tid = threadIdx.x, lane = tid & 63, wave = tid >> 6;
    const int srow = lane >> 3, scol = ((lane & 7) ^ srow) << 3;
    const int ln = lane & 15, kq = (lane >> 4) << 4;
    const int swz = (lane & 7) << 4;
    const int rA = wave * 32 + ln;
    const bf16* Wb = Wms + (size_t)nt * 32 * 1024;
    const bf16* Ab = hh + 1024;

    f32x4 acc[2][2];
#pragma unroll
    for (int m = 0; m < 2; ++m)
#pragma unroll
        for (int n = 0; n < 2; ++n) acc[m][n] = (f32x4){0.f, 0.f, 0.f, 0.f};

    for (int it = 0; it < 4; ++it) {
        if (it) __syncthreads();
        const int koff = it * 256;
#pragma unroll
        for (int kc = 0; kc < 4; ++kc) {
            const int kg = koff + kc * 64 + scol;
#pragma unroll
            for (int i = 0; i < 4; ++i) {
                int rb = i * 32 + wave * 8;
                GLL(Ab + (size_t)(rb + srow) * 2048 + kg, &sm.As[kc][rb][0]);
            }
            GLL(Wb + (size_t)(wave * 8 + srow) * 1024 + kg, &sm.Ws[kc][wave * 8][0]);
        }
        __syncthreads();
#pragma unroll
        for (int kc = 0; kc < 4; ++kc)
#pragma unroll
            for (int k2 = 0; k2 < 2; ++k2) {
                const int co = (((k2 << 6) | kq) ^ swz) >> 1;
                bf16x8 a0 = *(const bf16x8*)&sm.As[kc][rA][co];
                bf16x8 a1 = *(const bf16x8*)&sm.As[kc][rA + 16][co];
                bf16x8 b0 = *(const bf16x8*)&sm.Ws[kc][ln][co];
                bf16x8 b1 = *(const bf16x8*)&sm.Ws[kc][ln + 16][co];
                acc[0][0] = MFMA(a0, b0, acc[0][0], 0, 0, 0);
                acc[0][1] = MFMA(a0, b1, acc[0][1], 0, 0, 0);
                acc[1][0] = MFMA(a1, b0, acc[1][0], 0, 0, 0);
                acc[1][1] = MFMA(a1, b1, acc[1][1], 0, 0, 0);
            }
    }
    __syncthreads();

    float* Cl = (float*)&sm;
    const int q = lane >> 4;
#pragma unroll
    for (int f = 0; f < 2; ++f)
#pragma unroll
        for (int n = 0; n < 2; ++n)
#pragma unroll
            for (int r = 0; r < 4; ++r)
                Cl[(wave * 32 + f * 16 + q * 4 + r) * 33 + n * 16 + ln] = acc[f][n][r];
    __syncthreads();

#pragma unroll
    for (int it = 0; it < 8; ++it) {
        int li = it * 256 + tid;
        int row = li >> 4, zl = li & 15;
        int zi = nt * 16 + zl;
        float mu = Cl[row * 33 + zl * 2]     + b_mu[zi];
        float ls = Cl[row * 33 + zl * 2 + 1] + b_sig[zi];
        float z = eps_t[row * 256 + zi] * expf(ls) + mu;
        zbf[(size_t)row * 256 + zi] = (bf16)z;
    }
}

// ---------------------------------------------------------------------------
// kD (merged): dec z-part GEMM (K=256 one-shot) + gdhh slices + biases +
// LSTM -> hdec (hh[j]). grid 64. Proven structure from R6/R8.
// ---------------------------------------------------------------------------
struct SmemD {
    bf16 As[4][128][64];   // 64 KB
    bf16 Ws[4][64][64];    // 32 KB
};

__global__ __launch_bounds__(256) void kD_k(
    const bf16* __restrict__ zbf, const bf16* __restrict__ Wdz,
    const bf16* __restrict__ decP,
    const float* __restrict__ b_ihd, const float* __restrict__ b_hhd,
    float* __restrict__ c_dec, bf16* __restrict__ hh)
{
    __shared__ SmemD sm;
    const int nt = blockIdx.x;
    const int tid = threadIdx.x, lane = tid & 63, wave = tid >> 6;
    const int srow = lane >> 3, scol = ((lane & 7) ^ srow) << 3;
    const int ln = lane & 15, q = lane >> 4;
    const int kq = q << 4, swz = (lane & 7) << 4;
    const int wr = wave & 1, wc = wave >> 1;
    const bf16* Wb = Wdz + (size_t)nt * 64 * 256;

    f32x4 acc[4][2];
#pragma unroll
    for (int f = 0; f < 4; ++f)
#pragma unroll
        for (int n = 0; n < 2; ++n) acc[f][n] = (f32x4){0.f, 0.f, 0.f, 0.f};

#pragma unroll
    for (int kc = 0; kc < 4; ++kc) {
        const int kg = kc * 64 + scol;
#pragma unroll
        for (int i = 0; i < 4; ++i) {
            int rb = i * 32 + wave * 8;
            GLL(zbf + (size_t)(rb + srow) * 256 + kg, &sm.As[kc][rb][0]);
        }
#pragma unroll
        for (int i = 0; i < 2; ++i) {
            int rbw = i * 32 + wave * 8;
            GLL(Wb + (size_t)(rbw + srow) * 256 + kg, &sm.Ws[kc][rbw][0]);
        }
    }
    __syncthreads();
#pragma unroll
    for (int kc = 0; kc < 4; ++kc)
#pragma unroll
        for (int k2 = 0; k2 < 2; ++k2) {
            const int co = (((k2 << 6) | kq) ^ swz) >> 1;
            bf16x8 b0 = *(const bf16x8*)&sm.Ws[kc][wc * 32 + ln][co];
            bf16x8 b1 = *(const bf16x8*)&sm.Ws[kc][wc * 32 + ln + 16][co];
#pragma unroll
            for (int f = 0; f < 4; ++f) {
                bf16x8 a = *(const bf16x8*)&sm.As[kc][wr * 64 + f * 16 + ln][co];
                acc[f][0] = MFMA(a, b0, acc[f][0], 0, 0, 0);
                acc[f][1] = MFMA(a, b1, acc[f][1], 0, 0, 0);
            }
        }
    __syncthreads();

    float* Cl = (float*)&sm;
#pragma unroll
    for (int f = 0; f < 4; ++f)
#pragma unroll
        for (int n = 0; n < 2; ++n)
#pragma unroll
            for (int r = 0; r < 4; ++r)
                Cl[(wr * 64 + f * 16 + q * 4 + r) * 66 + wc * 32 + n * 16 + ln] = acc[f][n][r];
    __syncthreads();

#pragma unroll
    for (int it = 0; it < 8; ++it) {
        int li = it * 256 + tid;
        int row = li >> 4, jl = li & 15;
        int J = nt * 16 + jl;
        const float* cr = &Cl[row * 66 + jl * 4];
        int gcol = nt * 64 + jl * 4;
        const bf16* gp = decP + (size_t)row * 4096 + gcol;
        bf16x4 g0v = *(const bf16x4*)gp;
        bf16x4 g1v = *(const bf16x4*)(gp + SLICE);
        float gi = cr[0] + (float)g0v[0] + (float)g1v[0] + b_ihd[J]        + b_hhd[J];
        float gf = cr[1] + (float)g0v[1] + (float)g1v[1] + b_ihd[1024 + J] + b_hhd[1024 + J];
        float gg = cr[2] + (float)g0v[2] + (float)g1v[2] + b_ihd[2048 + J] + b_hhd[2048 + J];
        float go = cr[3] + (float)g0v[3] + (float)g1v[3] + b_ihd[3072 + J] + b_hhd[3072 + J];
        int ci = row * 1024 + J;
        float cn = sigf(gf) * c_dec[ci] + sigf(gi) * tanhf(gg);
        c_dec[ci] = cn;
        hh[(size_t)row * 2048 + J] = (bf16)(sigf(go) * tanhf(cn));
    }
}

// ---------------- init + weight packing ----------------
#define PBL (B_ * 4096)
#define PBH (B_ * 1024)

__global__ void init_k(const float* __restrict__ x, const float* __restrict__ c0,
                       const float* __restrict__ h0e, const float* __restrict__ h0d,
                       float* __restrict__ c_t, float* __restrict__ c_enc,
                       float* __restrict__ c_dec, bf16* __restrict__ negs,
                       bf16* __restrict__ hh, bf16* __restrict__ x_bf) {
    int i = blockIdx.x * 256 + threadIdx.x;
    if (i >= PBL) return;
    int n = i & 4095;
    float c = c0[n];
    c_t[i] = c;
    negs[i] = (bf16)(-sigf(c));
    x_bf[i] = (bf16)x[i];
    if (i < PBH) {
        int row = i >> 10, j = i & 1023;
        c_enc[i] = 0.f;
        c_dec[i] = 0.f;
        hh[(size_t)row * 2048 + j]        = (bf16)h0d[j];
        hh[(size_t)row * 2048 + 1024 + j] = (bf16)h0e[j];
    }
}

__device__ __forceinline__ bf16x8 cvt8(const float* s) {
    float4 a = *(const float4*)s, b = *(const float4*)(s + 4);
    bf16x8 v = { (bf16)a.x, (bf16)a.y, (bf16)a.z, (bf16)a.w,
                 (bf16)b.x, (bf16)b.y, (bf16)b.z, (bf16)b.w };
    return v;
}

// np = 4j+g <-> n = g*1024+j.  Wxh[np][4096], Wsum[np][4096],
// Wcat[np][0..1024)=Wih(hdec), Wcat[np][1024..2048)=Whh(henc).
__global__ void conv_es_k(const float* __restrict__ Wih, const float* __restrict__ Whh,
                          bf16* __restrict__ wxh, bf16* __restrict__ wsum,
                          bf16* __restrict__ wcat) {
    int id = blockIdx.x * 256 + threadIdx.x;
    if (id >= 4096 * 768) return;
    int np = id / 768, c = (id - np * 768) * 8;
    int n = ((np & 3) << 10) + (np >> 2);
    if (c < 4096) {
        const float* sx = Wih + (size_t)n * 9216 + c;
        const float* sh = sx + 4096;
        float4 a = *(const float4*)sh, b = *(const float4*)(sh + 4);
        float4 e = *(const float4*)sx, f = *(const float4*)(sx + 4);
        bf16x8 vh = { (bf16)a.x, (bf16)a.y, (bf16)a.z, (bf16)a.w,
                      (bf16)b.x, (bf16)b.y, (bf16)b.z, (bf16)b.w };
        bf16x8 vs = { (bf16)(a.x + e.x), (bf16)(a.y + e.y), (bf16)(a.z + e.z), (bf16)(a.w + e.w),
                      (bf16)(b.x + f.x), (bf16)(b.y + f.y), (bf16)(b.z + f.z), (bf16)(b.w + f.w) };
        *(bf16x8*)(wxh  + (size_t)np * 4096 + c) = vh;
        *(bf16x8*)(wsum + (size_t)np * 4096 + c) = vs;
    } else if (c < 5120) {
        *(bf16x8*)(wcat + (size_t)np * 2048 + (c - 4096)) =
            cvt8(Wih + (size_t)n * 9216 + 8192 + (c - 4096));
    } else {
        *(bf16x8*)(wcat + (size_t)np * 2048 + 1024 + (c - 5120)) =
            cvt8(Whh + (size_t)n * 1024 + (c - 5120));
    }
}

__global__ void conv_dec_k(const float* __restrict__ Wih, const float* __restrict__ Whh,
                           bf16* __restrict__ wdz, bf16* __restrict__ wdh) {
    int id = blockIdx.x * 256 + threadIdx.x;
    if (id >= 4096 * 160) return;
    int np = id / 160, c = (id - np * 160) * 8;
    int n = ((np & 3) << 10) + (np >> 2);
    if (c < 256)
        *(bf16x8*)(wdz + (size_t)np * 256 + c) = cvt8(Wih + (size_t)n * 256 + c);
    else
        *(bf16x8*)(wdh + (size_t)np * 1024 + (c - 256)) =
            cvt8(Whh + (size_t)n * 1024 + (c - 256));
}

// Wms[np][k]: np = 2*zi + s; s=0 -> Wmu[zi], s=1 -> Wsig[zi]
__global__ void conv_ms_k(const float* __restrict__ Wmu, const float* __restrict__ Wsig,
                          bf16* __restrict__ dst) {
    int id = blockIdx.x * 256 + threadIdx.x;
    if (id >= 512 * 128) return;
    int np = id >> 7, c = (id & 127) * 8;
    int zi = np >> 1;
    const float* src = ((np & 1) ? Wsig : Wmu) + (size_t)zi * 1024 + c;
    *(bf16x8*)(dst + (size_t)np * 1024 + c) = cvt8(src);
}

__global__ void conv_wr_k(const float* __restrict__ Wwr, bf16* __restrict__ dst) {
    int id = blockIdx.x * 256 + threadIdx.x;
    if (id >= 4096 * 128) return;
    *(bf16x8*)(dst + (size_t)id * 8) = cvt8(Wwr + (size_t)id * 8);
}

// ---------------- launch ----------------
extern "C" void kernel_launch(void* const* d_in, const int* in_sizes, int n_in,
                              void* d_out, int out_size, void* d_ws, size_t ws_size,
                              hipStream_t stream) {
    const float* x      = (const float*)d_in[0];
    const float* eps    = (const float*)d_in[1];
    const float* c0     = (const float*)d_in[2];
    const float* h0e    = (const float*)d_in[3];
    const float* h0d    = (const float*)d_in[4];
    const float* W_ih_e = (const float*)d_in[5];
    const float* b_ih_e = (const float*)d_in[6];
    const float* W_hh_e = (const float*)d_in[7];
    const float* b_hh_e = (const float*)d_in[8];
    const float* W_mu   = (const float*)d_in[9];
    const float* b_mu   = (const float*)d_in[10];
    const float* W_sig  = (const float*)d_in[11];
    const float* b_sig  = (const float*)d_in[12];
    const float* W_ih_d = (const float*)d_in[13];
    const float* b_ih_d = (const float*)d_in[14];
    const float* W_hh_d = (const float*)d_in[15];
    const float* b_hh_d = (const float*)d_in[16];
    const float* W_wr   = (const float*)d_in[17];
    const float* b_wr   = (const float*)d_in[18];
    float* out = (float*)d_out;

    float* f = (float*)d_ws;
    float* c_t   = f; f += SLICE;
    float* base  = f; f += SLICE;
    float* pP    = f; f += (size_t)4 * SLICE;    // fp32 prologue partials
    float* c_enc = f; f += 131072;
    float* c_dec = f; f += 131072;
    bf16* bp    = (bf16*)f;
    bf16* encP  = bp; bp += (size_t)12 * SLICE;  // 0-7: kA; 8-11: hdhe (kE)
    bf16* decP  = bp; bp += (size_t)2 * SLICE;   // gdhh slices
    bf16* wrP   = bp; bp += (size_t)2 * SLICE;
    bf16* negs  = bp; bp += (size_t)B_ * 4096;
    bf16* hh    = bp; bp += (size_t)B_ * 2048;   // [hdec | henc] per row
    bf16* zbf   = bp; bp += (size_t)B_ * 256;
    bf16* x_bf  = bp; bp += (size_t)B_ * 4096;
    bf16* Wxh   = bp; bp += (size_t)4096 * 4096;
    bf16* Wsum  = bp; bp += (size_t)4096 * 4096;
    bf16* Wcat  = bp; bp += (size_t)4096 * 2048;
    bf16* Wdz   = bp; bp += (size_t)4096 * 256;
    bf16* Wdh   = bp; bp += (size_t)4096 * 1024;
    bf16* Wms   = bp; bp += (size_t)512 * 1024;
    bf16* Wwr   = bp; bp += (size_t)4096 * 1024;

    dim3 blk(256);

    init_k<<<(PBL + 255) / 256, blk, 0, stream>>>(x, c0, h0e, h0d, c_t, c_enc, c_dec,
                                                  negs, hh, x_bf);
    conv_es_k<<<(4096 * 768 + 255) / 256, blk, 0, stream>>>(W_ih_e, W_hh_e,
                                                            Wxh, Wsum, Wcat);
    conv_dec_k<<<(4096 * 160 + 255) / 256, blk, 0, stream>>>(W_ih_d, W_hh_d, Wdz, Wdh);
    conv_ms_k<<<(512 * 128 + 255) / 256, blk, 0, stream>>>(W_mu, W_sig, Wms);
    conv_wr_k<<<(4096 * 128 + 255) / 256, blk, 0, stream>>>(W_wr, Wwr);

    // base = b_ih_e + b_hh_e + x @ Wsum^T  (gate-interleaved cols), fp32 z=4
    gemm64_k<<<dim3(64, 2, 4), blk, 0, stream>>>(x_bf, 4096, Wsum, 4096, 1024, pP);
    fin0_k<<<dim3(512), blk, 0, stream>>>(pP, base, b_ih_e, b_hh_e);

    // preloop: hdhe (encP 8-11) + gdhh (decP 0-1) from initial hh
    kE_k<<<dim3(64, 2, 6), blk, 0, stream>>>(hh, Wwr, Wcat, Wdh, wrP, encP, decP, 2);

    for (int t = 0; t < T_; ++t) {
        // kA: negs @ Wxh^T (K=4096), z=8, Kc=512 -> encP slices 0-7 (1024 blocks)
        gemm64b_k<<<dim3(64, 2, 8), blk, 0, stream>>>(negs, 4096, Wxh, 4096, 512, encP);
        // kB: sum 12 slices + base -> enc LSTM -> henc
        kB_k<<<dim3(512), blk, 0, stream>>>(encP, base, c_enc, hh);
        // kC: mu/sigma + reparam -> zbf
        kC_k<<<dim3(16), blk, 0, stream>>>(hh, Wms, b_mu, b_sig,
                                           eps + (size_t)t * (B_ * 256), zbf);
        // kD: dec z-GEMM + gdhh slices + LSTM -> hdec
        kD_k<<<dim3(64), blk, 0, stream>>>(zbf, Wdz, decP, b_ih_d, b_hh_d, c_dec, hh);
        // kE: wr (z=2) + hdhe (z=4) + gdhh (z=2), all nk=8 (1024 blocks)
        kE_k<<<dim3(64, 2, 8), blk, 0, stream>>>(hh, Wwr, Wcat, Wdh, wrP, encP, decP, 0);
        // kF: c_t += wr + b_wr -> negs (+ out at last step)
        kF_k<<<dim3(512), blk, 0, stream>>>(wrP, b_wr, c_t, negs,
                                            (t == T_ - 1) ? out : nullptr);
    }
}